// Round 3
// baseline (3583.467 us; speedup 1.0000x reference)
//
#include <hip/hip_runtime.h>
#include <math.h>

#define H   39
#define G4  156   // 4*H
#define TL  2048  // T
#define BB  512   // B

// =====================================================================
// K1: input-projection GEMM.
//   pre[b][dir][ss][j] = x[b][tx] . W_ih[dir][j][:] + b_ih[j] + b_hh[j]
//   tx = t0+ss (fwd) or TL-1-(t0+ss) (bwd)  -> pre is in PROCESSING order.
// grid (2*SP, 2): blockIdx.y = dir; 192 threads; each block does 256 rows.
// Thread j<156 owns one gate row (W row in 39 VGPRs, reused 256x).
// The x row is wave-uniform -> compiler emits s_load into SGPRs.
// =====================================================================
__global__ __launch_bounds__(192)
void lstm_pre_kernel(const float* __restrict__ x,
                     const float* __restrict__ W_ih_f, const float* __restrict__ b_ih_f,
                     const float* __restrict__ b_hh_f,
                     const float* __restrict__ W_ih_b, const float* __restrict__ b_ih_b,
                     const float* __restrict__ b_hh_b,
                     float* __restrict__ pre, int t0, int SP, int lsp)
{
    const int dir = blockIdx.y;
    const int j   = threadIdx.x;          // gate row when < 156
    const float* __restrict__ W_ih = dir ? W_ih_b : W_ih_f;
    const float* __restrict__ b_i  = dir ? b_ih_b : b_ih_f;
    const float* __restrict__ b_h  = dir ? b_hh_b : b_hh_f;

    float wih[H];
    float bias = 0.0f;
    if (j < G4) {
        #pragma unroll
        for (int k = 0; k < H; ++k) wih[k] = W_ih[j * H + k];
        bias = b_i[j] + b_h[j];
    } else {
        #pragma unroll
        for (int k = 0; k < H; ++k) wih[k] = 0.0f;
    }

    const int r0 = blockIdx.x * 256;
    for (int rr = 0; rr < 256; ++rr) {
        const int r  = r0 + rr;
        const int b  = r >> lsp;           // SP is pow2
        const int ss = r & (SP - 1);
        const int s  = t0 + ss;
        const int tx = dir ? (TL - 1 - s) : s;
        const float* __restrict__ xr = x + ((size_t)b * TL + tx) * H;
        float a0 = bias, a1 = 0.0f, a2 = 0.0f;
        #pragma unroll
        for (int k = 0; k < 39; k += 3) {        // 13 x 3 = 39
            a0 = fmaf(wih[k],     xr[k],     a0);
            a1 = fmaf(wih[k + 1], xr[k + 1], a1);
            a2 = fmaf(wih[k + 2], xr[k + 2], a2);
        }
        if (j < G4)
            pre[((size_t)(b * 2 + dir) * SP + ss) * G4 + j] = a0 + (a1 + a2);
    }
}

// =====================================================================
// K2: recurrence. One block per (b,dir), 192 threads (3 waves).
//   - h lives in SGPRs (39 v_readlane after each elementwise phase);
//     each wave recomputes h redundantly from the shared gates -> no
//     second barrier, no LDS broadcast reads.
//   - LDS per wave-step: 1 ds_write_b32 (gate) + 4 ds_read_b32 (EW).
//     (round-1 had ~11 ds_read_b128-class ops -> LDS-pipe bound.)
//   - pre[j] is per-lane: one coalesced prefetched global load per step.
//   - single __syncthreads per step; ping-pong gate buffers.
// =====================================================================
__global__ __launch_bounds__(192)
void lstm_rec_kernel(const float* __restrict__ pre,
                     const float* __restrict__ W_hh_f, const float* __restrict__ W_hh_b,
                     float* __restrict__ out, float* __restrict__ state,
                     int t0, int SP)
{
    const int blk = blockIdx.x;          // 0..1023
    const int b   = blk >> 1;
    const int dir = blk & 1;
    const int tid = threadIdx.x;
    const int lan = tid & 63;
    const int wav = tid >> 6;
    const int j   = tid;                 // gate row when < 156

    const float* __restrict__ W_hh = dir ? W_hh_b : W_hh_f;

    __shared__ float gates[2][192];

    float whh[H];
    if (j < G4) {
        #pragma unroll
        for (int k = 0; k < H; ++k) whh[k] = W_hh[j * H + k];
    } else {
        #pragma unroll
        for (int k = 0; k < H; ++k) whh[k] = 0.0f;
    }
    const bool  isg  = (j >= 2 * H) && (j < 3 * H);   // tanh rows
    const float amul = isg ? 2.0f : 1.0f;
    const float aoff = isg ? -1.0f : 0.0f;

    const float* __restrict__ prow = pre + (size_t)(b * 2 + dir) * SP * G4;
    float* __restrict__ orow = out + (size_t)b * (TL * 2 * H) + dir * H;
    float* __restrict__ st   = state + blk * 80;

    // ---- initial h -> SGPRs, c -> lane-private (lanes 0..38 of every wave)
    float c  = 0.0f;
    float hv = 0.0f;
    if (t0 != 0 && lan < H) {
        hv = st[lan];
        c  = st[40 + lan];
    }
    int sh[H];
    {
        const int hb = __float_as_int(hv);
        #pragma unroll
        for (int k = 0; k < H; ++k) sh[k] = __builtin_amdgcn_readlane(hb, k);
    }

    float pv = (j < G4) ? prow[j] : 0.0f;     // pre for ss=0

    for (int ss = 0; ss < SP; ++ss) {
        // prefetch next step's pre (latency hidden across the whole step)
        float pn = 0.0f;
        if (j < G4 && (ss + 1) < SP) pn = prow[(size_t)(ss + 1) * G4 + j];

        if (j < G4) {
            float a0 = pv, a1 = 0.0f, a2 = 0.0f;
            #pragma unroll
            for (int k = 0; k < 39; k += 3) {     // h . W_hh row, SGPR h operand
                a0 = fmaf(whh[k],     __int_as_float(sh[k]),     a0);
                a1 = fmaf(whh[k + 1], __int_as_float(sh[k + 1]), a1);
                a2 = fmaf(whh[k + 2], __int_as_float(sh[k + 2]), a2);
            }
            const float tot  = a0 + (a1 + a2);
            // sigmoid for i/f/o rows; tanh(x) = 2*sigmoid(2x)-1 for g rows
            const float targ = amul * tot;
            const float act  = fmaf(amul,
                                    __builtin_amdgcn_rcpf(1.0f + __expf(-targ)),
                                    aoff);
            gates[ss & 1][j] = act;
        }
        __syncthreads();     // single barrier: gates visible to all waves

        if (lan < H) {       // every wave redundantly computes h for its lanes
            const float* g = gates[ss & 1];
            const float ig = g[lan];
            const float fg = g[H + lan];
            const float gg = g[2 * H + lan];
            const float og = g[3 * H + lan];
            c = fmaf(fg, c, ig * gg);
            const float e2 = __expf(-2.0f * c);
            const float th = fmaf(2.0f, __builtin_amdgcn_rcpf(1.0f + e2), -1.0f);
            hv = og * th;
            if (wav == 0) orow[(size_t)(t0 + ss) * (2 * H) + lan] = hv;
        }
        {   // broadcast h to SGPRs for the next GEMV (intra-wave, no barrier)
            const int hb = __float_as_int(hv);
            #pragma unroll
            for (int k = 0; k < H; ++k) sh[k] = __builtin_amdgcn_readlane(hb, k);
        }
        pv = pn;
    }

    if (wav == 0 && lan < H) {           // carry state to next chunk
        st[lan]      = hv;
        st[40 + lan] = c;
    }
}

// =====================================================================
// Fallback (round-1 kernel, verbatim): used only if workspace is unusable.
// =====================================================================
__global__ __launch_bounds__(320, 5)
void lstm_bidir_fallback(const float* __restrict__ x,
                         const float* __restrict__ W_ih_f, const float* __restrict__ W_hh_f,
                         const float* __restrict__ b_ih_f, const float* __restrict__ b_hh_f,
                         const float* __restrict__ W_ih_b, const float* __restrict__ W_hh_b,
                         const float* __restrict__ b_ih_b, const float* __restrict__ b_hh_b,
                         float* __restrict__ out)
{
    const int blk = blockIdx.x;
    const int b   = blk >> 1;
    const int dir = blk & 1;
    const int tid = threadIdx.x;
    const int j   = tid >> 1;
    const int p   = tid & 1;
    const bool rowActive = (tid < 2 * G4);

    const float* __restrict__ W_ih = dir ? W_ih_b : W_ih_f;
    const float* __restrict__ W_hh = dir ? W_hh_b : W_hh_f;
    const float* __restrict__ b_ih = dir ? b_ih_b : b_ih_f;
    const float* __restrict__ b_hh = dir ? b_hh_b : b_hh_f;

    __shared__ __align__(16) float xbf[40];
    __shared__ __align__(16) float hbf[40];
    __shared__ float gates[G4];
    float4* xb4 = (float4*)xbf;
    float4* hb4 = (float4*)hbf;

    float4 wih[5], whh[5];
    float bias = 0.0f;
    if (rowActive) {
        #pragma unroll
        for (int m = 0; m < 5; ++m) {
            const int k0 = 8 * m + 4 * p;
            float a[4], hh[4];
            #pragma unroll
            for (int e = 0; e < 4; ++e) {
                const int k = k0 + e;
                a[e]  = (k < H) ? W_ih[j * H + k] : 0.0f;
                hh[e] = (k < H) ? W_hh[j * H + k] : 0.0f;
            }
            wih[m] = make_float4(a[0], a[1], a[2], a[3]);
            whh[m] = make_float4(hh[0], hh[1], hh[2], hh[3]);
        }
        bias = b_ih[j] + b_hh[j];
    }
    const bool  isg  = (j >= 2 * H) && (j < 3 * H);
    const float amul = isg ? 2.0f : 1.0f;
    const float aoff = isg ? -1.0f : 0.0f;

    const float* __restrict__ xrow = x + (size_t)b * (TL * H);
    float* __restrict__ orow = out + (size_t)b * (TL * 2 * H) + dir * H;

    float c = 0.0f;
    if (tid < 40) {
        hbf[tid] = 0.0f;
        const int t0 = dir ? (TL - 1) : 0;
        xbf[tid] = (tid < H) ? xrow[(size_t)t0 * H + tid] : 0.0f;
    }
    __syncthreads();

    for (int s = 0; s < TL; ++s) {
        float xnext = 0.0f;
        if (tid < H && (s + 1) < TL) {
            const int tn = dir ? (TL - 2 - s) : (s + 1);
            xnext = xrow[(size_t)tn * H + tid];
        }
        if (rowActive) {
            float4 acc = make_float4(0.0f, 0.0f, 0.0f, 0.0f);
            #pragma unroll
            for (int m = 0; m < 5; ++m) {
                const int ci = 2 * m + p;
                const float4 xv = xb4[ci];
                const float4 hv = hb4[ci];
                acc.x = fmaf(wih[m].x, xv.x, fmaf(whh[m].x, hv.x, acc.x));
                acc.y = fmaf(wih[m].y, xv.y, fmaf(whh[m].y, hv.y, acc.y));
                acc.z = fmaf(wih[m].z, xv.z, fmaf(whh[m].z, hv.z, acc.z));
                acc.w = fmaf(wih[m].w, xv.w, fmaf(whh[m].w, hv.w, acc.w));
            }
            float psum = (acc.x + acc.y) + (acc.z + acc.w);
            const float tot  = psum + __shfl_xor(psum, 1) + bias;
            const float targ = amul * tot;
            const float e    = __expf(-targ);
            const float act  = fmaf(amul, __builtin_amdgcn_rcpf(1.0f + e), aoff);
            if (p == 0) gates[j] = act;
        }
        __syncthreads();
        if (tid < H) {
            const float ig = gates[tid];
            const float fg = gates[H + tid];
            const float gg = gates[2 * H + tid];
            const float og = gates[3 * H + tid];
            c = fmaf(fg, c, ig * gg);
            const float e2 = __expf(-2.0f * c);
            const float th = fmaf(2.0f, __builtin_amdgcn_rcpf(1.0f + e2), -1.0f);
            const float h  = og * th;
            hbf[tid] = h;
            xbf[tid] = xnext;
            orow[(size_t)s * (2 * H) + tid] = h;
        }
        __syncthreads();
    }
}

extern "C" void kernel_launch(void* const* d_in, const int* in_sizes, int n_in,
                              void* d_out, int out_size, void* d_ws, size_t ws_size,
                              hipStream_t stream) {
    const float* x      = (const float*)d_in[0];
    const float* W_ih_f = (const float*)d_in[1];
    const float* W_hh_f = (const float*)d_in[2];
    const float* b_ih_f = (const float*)d_in[3];
    const float* b_hh_f = (const float*)d_in[4];
    const float* W_ih_b = (const float*)d_in[5];
    const float* W_hh_b = (const float*)d_in[6];
    const float* b_ih_b = (const float*)d_in[7];
    const float* b_hh_b = (const float*)d_in[8];
    float* out = (float*)d_out;

    // choose the largest pow2 chunk SP whose pre-buffer fits the workspace
    int SP = TL;
    while (SP >= 32) {
        const size_t need = (size_t)(1 << 20) /* state region */
                          + (size_t)BB * 2 * SP * G4 * sizeof(float);
        if (need <= ws_size) break;
        SP >>= 1;
    }

    if (d_ws != nullptr && SP >= 32) {
        float* state = (float*)d_ws;                       // 1024*80 floats used
        float* pre   = (float*)((char*)d_ws + (1 << 20));  // chunk pre-buffer
        const int lsp = __builtin_ctz((unsigned)SP);
        for (int t0 = 0; t0 < TL; t0 += SP) {
            dim3 g1(2 * SP, 2);          // (BB*SP/256 blocks, dir)
            lstm_pre_kernel<<<g1, 192, 0, stream>>>(
                x, W_ih_f, b_ih_f, b_hh_f, W_ih_b, b_ih_b, b_hh_b,
                pre, t0, SP, lsp);
            lstm_rec_kernel<<<BB * 2, 192, 0, stream>>>(
                pre, W_hh_f, W_hh_b, out, state, t0, SP);
        }
    } else {
        lstm_bidir_fallback<<<BB * 2, 320, 0, stream>>>(
            x, W_ih_f, W_hh_f, b_ih_f, b_hh_f,
            W_ih_b, W_hh_b, b_ih_b, b_hh_b, out);
    }
}